// Round 1
// baseline (150.970 us; speedup 1.0000x reference)
//
#include <hip/hip_runtime.h>

static constexpr int B = 16, S = 4096, H = 1024, W = 1024;
static constexpr int NC = 8;             // number of S-chunks
static constexpr int CS = S / NC;        // 512 chunk size
static constexpr int LOG2_CS = 9;

// ---------------------------------------------------------------------------
// Kernel 1: chunk-local inclusive prefix sum along S.
// grid = B * NC * (H/256) = 512 blocks, 256 threads.
// Each thread owns one h-column within one chunk; loads/stores are fully
// coalesced (256 consecutive h per block = 1 KB per row).
// ---------------------------------------------------------------------------
__global__ void k_chunk_prefix(const float* __restrict__ hs, float* __restrict__ L) {
    const int HB = H / 256;                      // 4
    int blk = blockIdx.x;
    int hc = blk % HB;
    int c  = (blk / HB) % NC;
    int b  = blk / (HB * NC);
    int h  = hc * 256 + threadIdx.x;
    size_t base = ((size_t)b * S + (size_t)c * CS) * H + h;
    float acc = 0.f;
#pragma unroll 8
    for (int s = 0; s < CS; ++s) {
        acc += hs[base + (size_t)s * H];
        L[base + (size_t)s * H] = acc;
    }
}

// ---------------------------------------------------------------------------
// Kernel 2: exclusive coarse prefix of chunk totals.
// CT[b,c,h] = sum over chunks c' < c of chunk-total(c').
// Chunk totals are just the last row of each chunk in L. Tiny kernel.
// grid = B * (H/256) = 64 blocks, 256 threads.
// ---------------------------------------------------------------------------
__global__ void k_coarse(const float* __restrict__ L, float* __restrict__ CT) {
    const int HB = H / 256;
    int hc = blockIdx.x % HB;
    int b  = blockIdx.x / HB;
    int h  = hc * 256 + threadIdx.x;
    float acc = 0.f;
    for (int c = 0; c < NC; ++c) {
        CT[((size_t)b * NC + c) * H + h] = acc;
        acc += L[((size_t)b * S + (size_t)c * CS + (CS - 1)) * H + h];
    }
}

// ---------------------------------------------------------------------------
// Kernel 3: gather. One block per (b,w); 256 threads x float4 covers H=1024.
// E_incl[s] = L[s] + CT[s >> LOG2_CS]; sum(start..end) = E[end] - E[start-1].
// Also writes the mask (as float 0/1) and zeros invalid rows.
// ---------------------------------------------------------------------------
__global__ void k_gather(const float* __restrict__ L, const float* __restrict__ CT,
                         const int* __restrict__ widx, const int* __restrict__ mwl,
                         float* __restrict__ out, float* __restrict__ mask) {
    int w = blockIdx.x % W;
    int b = blockIdx.x / W;
    int t = threadIdx.x;

    bool valid = (w < mwl[b]);
    size_t orow = ((size_t)b * W + w) * H;
    if (t == 0) mask[(size_t)b * W + w] = valid ? 1.0f : 0.0f;

    if (!valid) {
        float4 z = make_float4(0.f, 0.f, 0.f, 0.f);
        *(float4*)(out + orow + (size_t)t * 4) = z;
        return;
    }

    int start = widx[((size_t)b * W + w) * 2 + 0];
    int end   = widx[((size_t)b * W + w) * 2 + 1];
    float invLen = 1.0f / (float)(end - start + 1);

    int ce = end >> LOG2_CS;
    const float4 ve  = *(const float4*)(L  + ((size_t)b * S + end) * H + (size_t)t * 4);
    const float4 cte = *(const float4*)(CT + ((size_t)b * NC + ce) * H + (size_t)t * 4);

    float sx = ve.x + cte.x, sy = ve.y + cte.y, sz = ve.z + cte.z, sw = ve.w + cte.w;

    if (start > 0) {
        int sm = start - 1;
        int cs = sm >> LOG2_CS;
        const float4 vs  = *(const float4*)(L  + ((size_t)b * S + sm) * H + (size_t)t * 4);
        const float4 cts = *(const float4*)(CT + ((size_t)b * NC + cs) * H + (size_t)t * 4);
        sx -= vs.x + cts.x; sy -= vs.y + cts.y; sz -= vs.z + cts.z; sw -= vs.w + cts.w;
    }

    float4 o = make_float4(sx * invLen, sy * invLen, sz * invLen, sw * invLen);
    *(float4*)(out + orow + (size_t)t * 4) = o;
}

// ---------------------------------------------------------------------------
// Fallback: direct summation if workspace is too small. Correct but slow.
// ---------------------------------------------------------------------------
__global__ void k_direct(const float* __restrict__ hs, const int* __restrict__ widx,
                         const int* __restrict__ mwl, float* __restrict__ out,
                         float* __restrict__ mask) {
    int w = blockIdx.x % W;
    int b = blockIdx.x / W;
    int t = threadIdx.x;
    bool valid = (w < mwl[b]);
    size_t orow = ((size_t)b * W + w) * H;
    if (t == 0) mask[(size_t)b * W + w] = valid ? 1.0f : 0.0f;

    float4 acc = make_float4(0.f, 0.f, 0.f, 0.f);
    if (valid) {
        int start = widx[((size_t)b * W + w) * 2 + 0];
        int end   = widx[((size_t)b * W + w) * 2 + 1];
        float inv = 1.0f / (float)(end - start + 1);
        for (int s = start; s <= end; ++s) {
            const float4 v = *(const float4*)(hs + ((size_t)b * S + s) * H + (size_t)t * 4);
            acc.x += v.x; acc.y += v.y; acc.z += v.z; acc.w += v.w;
        }
        acc.x *= inv; acc.y *= inv; acc.z *= inv; acc.w *= inv;
    }
    *(float4*)(out + orow + (size_t)t * 4) = acc;
}

extern "C" void kernel_launch(void* const* d_in, const int* in_sizes, int n_in,
                              void* d_out, int out_size, void* d_ws, size_t ws_size,
                              hipStream_t stream) {
    const float* hs  = (const float*)d_in[0];
    const int*  widx = (const int*)d_in[1];
    const int*  mwl  = (const int*)d_in[2];
    float* out  = (float*)d_out;
    float* mask = out + (size_t)B * W * H;   // masks follow embeddings, flat

    const size_t Lbytes  = (size_t)B * S * H * sizeof(float);    // 256 MiB
    const size_t CTbytes = (size_t)B * NC * H * sizeof(float);   // 512 KiB

    if (ws_size >= Lbytes + CTbytes) {
        float* L  = (float*)d_ws;
        float* CT = (float*)((char*)d_ws + Lbytes);
        hipLaunchKernelGGL(k_chunk_prefix, dim3(B * NC * (H / 256)), dim3(256), 0, stream, hs, L);
        hipLaunchKernelGGL(k_coarse,       dim3(B * (H / 256)),      dim3(256), 0, stream, L, CT);
        hipLaunchKernelGGL(k_gather,       dim3(B * W),              dim3(256), 0, stream,
                           L, CT, widx, mwl, out, mask);
    } else {
        hipLaunchKernelGGL(k_direct, dim3(B * W), dim3(256), 0, stream, hs, widx, mwl, out, mask);
    }
}

// Round 2
// 113.541 us; speedup vs baseline: 1.3296x; 1.3296x over previous
//
#include <hip/hip_runtime.h>

static constexpr int B = 16, S = 4096, H = 1024, W = 1024;
static constexpr int NC = 64;            // number of S-chunks
static constexpr int CS = S / NC;        // 64 chunk size
static constexpr int LOG2_CS = 6;
static constexpr int BMW = S / 32;       // 128 bitmap words per batch

// ---------------------------------------------------------------------------
// Kernel 0: set one bit per needed prefix row (end, start-1 of valid words).
// Bitmap is zeroed by hipMemsetAsync before this.
// ---------------------------------------------------------------------------
__global__ void k_bitset(const int* __restrict__ widx, const int* __restrict__ mwl,
                         unsigned* __restrict__ bm) {
    int tid = blockIdx.x * 256 + threadIdx.x;
    if (tid >= B * W) return;
    int b = tid / W, w = tid % W;
    if (w >= mwl[b]) return;
    int start = widx[tid * 2 + 0];
    int end   = widx[tid * 2 + 1];
    atomicOr(&bm[b * BMW + (end >> 5)], 1u << (end & 31));
    if (start > 0) {
        int sm = start - 1;
        atomicOr(&bm[b * BMW + (sm >> 5)], 1u << (sm & 31));
    }
}

// ---------------------------------------------------------------------------
// Kernel 1: chunk-local inclusive prefix along S; store ONLY flagged rows.
// Chunk total always stored densely to CTraw. float4 per lane, 256 threads
// cover H=1024. grid = B*NC = 1024 blocks.
// ---------------------------------------------------------------------------
__global__ void __launch_bounds__(256)
k_chunk_prefix(const float* __restrict__ hs, const unsigned* __restrict__ bm,
               float* __restrict__ L, float* __restrict__ CTraw) {
    int c = blockIdx.x % NC;
    int b = blockIdx.x / NC;
    int col = threadIdx.x * 4;
    size_t rowbase = ((size_t)b * S + (size_t)c * CS) * H + col;
    unsigned bw0 = bm[b * BMW + c * 2 + 0];   // bits for s in [0,32)
    unsigned bw1 = bm[b * BMW + c * 2 + 1];   // bits for s in [32,64)
    float4 acc = make_float4(0.f, 0.f, 0.f, 0.f);
#pragma unroll 8
    for (int s = 0; s < CS; ++s) {
        float4 v = *(const float4*)(hs + rowbase + (size_t)s * H);
        acc.x += v.x; acc.y += v.y; acc.z += v.z; acc.w += v.w;
        unsigned bits = (s < 32) ? (bw0 >> s) : (bw1 >> (s - 32));
        if (bits & 1u)
            *(float4*)(L + rowbase + (size_t)s * H) = acc;
    }
    *(float4*)(CTraw + ((size_t)b * NC + c) * H + col) = acc;
}

// ---------------------------------------------------------------------------
// Kernel 2: exclusive prefix of chunk totals along c. grid = B*(H/256),
// 256 threads, one scalar column each. 8 MB total traffic.
// ---------------------------------------------------------------------------
__global__ void k_coarse(const float* __restrict__ CTraw, float* __restrict__ CTp) {
    int hc = blockIdx.x % (H / 256);
    int b  = blockIdx.x / (H / 256);
    int h  = hc * 256 + threadIdx.x;
    float acc = 0.f;
#pragma unroll 8
    for (int c = 0; c < NC; ++c) {
        size_t idx = ((size_t)b * NC + c) * H + h;
        CTp[idx] = acc;
        acc += CTraw[idx];
    }
}

// ---------------------------------------------------------------------------
// Kernel 3: gather. One wave (64 lanes) per word; 4 float4 per lane covers
// H=1024. 4 words per 256-thread block -> grid = B*W/4 = 4096.
// All branches are wave-uniform.
// ---------------------------------------------------------------------------
__global__ void __launch_bounds__(256)
k_gather(const float* __restrict__ L, const float* __restrict__ CTp,
         const int* __restrict__ widx, const int* __restrict__ mwl,
         float* __restrict__ out, float* __restrict__ mask) {
    int t = threadIdx.x;
    int wid = t >> 6, lane = t & 63;
    int word = blockIdx.x * 4 + wid;
    int b = word / W, w = word % W;
    size_t orow = (size_t)word * H;

    bool valid = (w < mwl[b]);
    if (lane == 0) mask[word] = valid ? 1.0f : 0.0f;

    if (!valid) {
        float4 z = make_float4(0.f, 0.f, 0.f, 0.f);
#pragma unroll
        for (int k = 0; k < 4; ++k)
            *(float4*)(out + orow + k * 256 + lane * 4) = z;
        return;
    }

    int start = widx[word * 2 + 0];
    int end   = widx[word * 2 + 1];
    float inv = 1.0f / (float)(end - start + 1);
    int ce = end >> LOG2_CS;
    const float* Le = L   + ((size_t)b * S + end) * H;
    const float* Ce = CTp + ((size_t)b * NC + ce) * H;
    bool has_s = (start > 0);
    const float* Ls = Le; const float* Cs = Ce;   // dummies, overwritten if used
    if (has_s) {
        int sm = start - 1, cs = sm >> LOG2_CS;
        Ls = L   + ((size_t)b * S + sm) * H;
        Cs = CTp + ((size_t)b * NC + cs) * H;
    }

#pragma unroll
    for (int k = 0; k < 4; ++k) {
        int off = k * 256 + lane * 4;
        float4 e  = *(const float4*)(Le + off);
        float4 ct = *(const float4*)(Ce + off);
        float sx = e.x + ct.x, sy = e.y + ct.y, sz = e.z + ct.z, sw = e.w + ct.w;
        if (has_s) {
            float4 s4 = *(const float4*)(Ls + off);
            float4 c4 = *(const float4*)(Cs + off);
            sx -= s4.x + c4.x; sy -= s4.y + c4.y; sz -= s4.z + c4.z; sw -= s4.w + c4.w;
        }
        float4 o = make_float4(sx * inv, sy * inv, sz * inv, sw * inv);
        *(float4*)(out + orow + off) = o;
    }
}

// ---------------------------------------------------------------------------
// Fallback: direct summation if workspace is too small. Correct but slow.
// ---------------------------------------------------------------------------
__global__ void k_direct(const float* __restrict__ hs, const int* __restrict__ widx,
                         const int* __restrict__ mwl, float* __restrict__ out,
                         float* __restrict__ mask) {
    int w = blockIdx.x % W;
    int b = blockIdx.x / W;
    int t = threadIdx.x;
    bool valid = (w < mwl[b]);
    size_t orow = ((size_t)b * W + w) * H;
    if (t == 0) mask[(size_t)b * W + w] = valid ? 1.0f : 0.0f;

    float4 acc = make_float4(0.f, 0.f, 0.f, 0.f);
    if (valid) {
        int start = widx[((size_t)b * W + w) * 2 + 0];
        int end   = widx[((size_t)b * W + w) * 2 + 1];
        float inv = 1.0f / (float)(end - start + 1);
        for (int s = start; s <= end; ++s) {
            const float4 v = *(const float4*)(hs + ((size_t)b * S + s) * H + (size_t)t * 4);
            acc.x += v.x; acc.y += v.y; acc.z += v.z; acc.w += v.w;
        }
        acc.x *= inv; acc.y *= inv; acc.z *= inv; acc.w *= inv;
    }
    *(float4*)(out + orow + (size_t)t * 4) = acc;
}

extern "C" void kernel_launch(void* const* d_in, const int* in_sizes, int n_in,
                              void* d_out, int out_size, void* d_ws, size_t ws_size,
                              hipStream_t stream) {
    const float* hs  = (const float*)d_in[0];
    const int*  widx = (const int*)d_in[1];
    const int*  mwl  = (const int*)d_in[2];
    float* out  = (float*)d_out;
    float* mask = out + (size_t)B * W * H;   // masks follow embeddings, flat

    const size_t Lbytes  = (size_t)B * S * H * sizeof(float);      // 256 MiB
    const size_t CTbytes = (size_t)B * NC * H * sizeof(float);     // 4 MiB
    const size_t BMbytes = (size_t)B * BMW * sizeof(unsigned);     // 8 KiB

    if (ws_size >= Lbytes + 2 * CTbytes + BMbytes) {
        float* L      = (float*)d_ws;
        float* CTraw  = (float*)((char*)d_ws + Lbytes);
        float* CTp    = (float*)((char*)d_ws + Lbytes + CTbytes);
        unsigned* bm  = (unsigned*)((char*)d_ws + Lbytes + 2 * CTbytes);

        hipMemsetAsync(bm, 0, BMbytes, stream);
        hipLaunchKernelGGL(k_bitset,       dim3((B * W + 255) / 256), dim3(256), 0, stream,
                           widx, mwl, bm);
        hipLaunchKernelGGL(k_chunk_prefix, dim3(B * NC),              dim3(256), 0, stream,
                           hs, bm, L, CTraw);
        hipLaunchKernelGGL(k_coarse,       dim3(B * (H / 256)),       dim3(256), 0, stream,
                           CTraw, CTp);
        hipLaunchKernelGGL(k_gather,       dim3(B * W / 4),           dim3(256), 0, stream,
                           L, CTp, widx, mwl, out, mask);
    } else {
        hipLaunchKernelGGL(k_direct, dim3(B * W), dim3(256), 0, stream, hs, widx, mwl, out, mask);
    }
}